// Round 1
// baseline (197.481 us; speedup 1.0000x reference)
//
#include <hip/hip_runtime.h>
#include <math.h>

#define NPTS 16384
#define DIM  16
#define KA   18      // 16 components + 2 augmented (norm terms folded into the dot)
#define TILE 128
#define NTILES (NPTS / TILE)   // 128

// ---------------------------------------------------------------------------
// prep: x' = rx*[x, -||x||^2/2, 1]  (isX=1)   y' = ry*[y, 1, -||y||^2/2] (isX=0)
// so that <x',y'> = -0.5 * rx * ry * sqdist  (acc <= 0; closest pair = max acc)
// Output layout: dst[k][point]  (K-major, so pairs-kernel staging is coalesced)
// ---------------------------------------------------------------------------
__global__ __launch_bounds__(256) void prep_kernel(const float* __restrict__ src,
                                                   float* __restrict__ dst,
                                                   int isX) {
    int i = blockIdx.x * 256 + threadIdx.x;
    if (i >= NPTS) return;
    const float4* s4 = (const float4*)(src + (size_t)i * DIM);
    float4 a = s4[0], b = s4[1], c = s4[2], d = s4[3];
    float v[DIM] = {a.x,a.y,a.z,a.w, b.x,b.y,b.z,b.w,
                    c.x,c.y,c.z,c.w, d.x,d.y,d.z,d.w};
    float n2 = 0.f;
#pragma unroll
    for (int k = 0; k < DIM; ++k) n2 = fmaf(v[k], v[k], n2);
    float r = 1.0f / (1.0f - n2);      // norms < 0.7 -> 1-n2 >= 0.51, safe
#pragma unroll
    for (int k = 0; k < DIM; ++k) dst[k * NPTS + i] = r * v[k];
    if (isX) { dst[16 * NPTS + i] = -0.5f * r * n2; dst[17 * NPTS + i] = r; }
    else     { dst[16 * NPTS + i] = r;              dst[17 * NPTS + i] = -0.5f * r * n2; }
}

// ---------------------------------------------------------------------------
// pairs: one block = one 128x128 tile. 256 threads as 16x16, each thread an
// 8x8 register tile. acc = <x',y'>; row/col maxes reduced through LDS.
// Rpart[bj][row]  = max over cols of tile-col-stripe bj
// Cpart[bi][col]  = max over rows of tile-row-stripe bi
// ---------------------------------------------------------------------------
__global__ __launch_bounds__(256, 2) void pairs_kernel(const float* __restrict__ Xp,
                                                       const float* __restrict__ Yp,
                                                       float* __restrict__ Rpart,
                                                       float* __restrict__ Cpart) {
    __shared__ float Xs[KA][TILE];
    __shared__ float Ys[KA][TILE];
    __shared__ float red[16][TILE];

    const int bi = blockIdx.x, bj = blockIdx.y;
    const int tid = threadIdx.x;
    const int tx = tid & 15, ty = tid >> 4;

    // stage 18x128 fp32 tiles of X' and Y' (coalesced float4)
    for (int e = tid; e < KA * TILE / 4; e += 256) {
        int k  = e >> 5;              // row (32 float4 per row)
        int c4 = (e & 31) << 2;       // col
        ((float4*)Xs)[e] = *(const float4*)(Xp + (size_t)k * NPTS + bi * TILE + c4);
        ((float4*)Ys)[e] = *(const float4*)(Yp + (size_t)k * NPTS + bj * TILE + c4);
    }
    __syncthreads();

    float acc[8][8];
#pragma unroll
    for (int a2 = 0; a2 < 8; ++a2)
#pragma unroll
        for (int b2 = 0; b2 < 8; ++b2) acc[a2][b2] = 0.f;

#pragma unroll
    for (int k = 0; k < KA; ++k) {
        float4 x0 = *(const float4*)&Xs[k][tx * 8];
        float4 x1 = *(const float4*)&Xs[k][tx * 8 + 4];
        float4 y0 = *(const float4*)&Ys[k][ty * 8];
        float4 y1 = *(const float4*)&Ys[k][ty * 8 + 4];
        float xs[8] = {x0.x,x0.y,x0.z,x0.w, x1.x,x1.y,x1.z,x1.w};
        float ys[8] = {y0.x,y0.y,y0.z,y0.w, y1.x,y1.y,y1.z,y1.w};
#pragma unroll
        for (int a2 = 0; a2 < 8; ++a2)
#pragma unroll
            for (int b2 = 0; b2 < 8; ++b2)
                acc[a2][b2] = fmaf(xs[a2], ys[b2], acc[a2][b2]);
    }

    // ---- row winners (max over this thread's 8 cols), reduce over ty ----
#pragma unroll
    for (int a2 = 0; a2 < 8; ++a2) {
        float m = acc[a2][0];
#pragma unroll
        for (int b2 = 1; b2 < 8; ++b2) m = fmaxf(m, acc[a2][b2]);
        red[ty][tx * 8 + a2] = m;
    }
    __syncthreads();
    if (tid < TILE) {
        float m = red[0][tid];
#pragma unroll
        for (int t = 1; t < 16; ++t) m = fmaxf(m, red[t][tid]);
        Rpart[(size_t)bj * NPTS + bi * TILE + tid] = m;
    }
    __syncthreads();

    // ---- col winners (max over this thread's 8 rows), reduce over tx ----
#pragma unroll
    for (int b2 = 0; b2 < 8; ++b2) {
        float m = acc[0][b2];
#pragma unroll
        for (int a2 = 1; a2 < 8; ++a2) m = fmaxf(m, acc[a2][b2]);
        red[tx][ty * 8 + b2] = m;
    }
    __syncthreads();
    if (tid < TILE) {
        float m = red[0][tid];
#pragma unroll
        for (int t = 1; t < 16; ++t) m = fmaxf(m, red[t][tid]);
        Cpart[(size_t)bi * NPTS + bj * TILE + tid] = m;
    }
}

// ---------------------------------------------------------------------------
// finalize: reduce 128 partials per point, arcosh, mean, atomic-add scalar.
// u-1 = t = -4*maxacc ;  arcosh(1+t) = log1p(t + sqrt(t*(t+2)))
// blocks 0..63 handle rows (term1), 64..127 handle cols (term2)
// ---------------------------------------------------------------------------
__global__ __launch_bounds__(256) void finalize_kernel(const float* __restrict__ Rpart,
                                                       const float* __restrict__ Cpart,
                                                       float* __restrict__ out) {
    int idx = blockIdx.x * 256 + threadIdx.x;
    const bool isRow = (idx < NPTS);                 // uniform per block (256 | 16384)
    const float* P = isRow ? Rpart : Cpart;
    int i = isRow ? idx : idx - NPTS;
    float m = P[i];
    for (int s = 1; s < NTILES; ++s) m = fmaxf(m, P[(size_t)s * NPTS + i]);
    float t = -4.0f * m;                             // = u - 1 >= 0
    float d = log1pf(t + sqrtf(t * (t + 2.0f)));     // arcosh(u)
    float val = d * (1.0f / NPTS);

    __shared__ float sred[256];
    sred[threadIdx.x] = val;
    __syncthreads();
    for (int s = 128; s > 0; s >>= 1) {
        if (threadIdx.x < s) sred[threadIdx.x] += sred[threadIdx.x + s];
        __syncthreads();
    }
    if (threadIdx.x == 0) atomicAdd(out, sred[0]);
}

// ---------------------------------------------------------------------------
extern "C" void kernel_launch(void* const* d_in, const int* in_sizes, int n_in,
                              void* d_out, int out_size, void* d_ws, size_t ws_size,
                              hipStream_t stream) {
    const float* set1 = (const float*)d_in[0];
    const float* set2 = (const float*)d_in[1];
    float* out = (float*)d_out;

    // workspace layout (floats):
    //   Xp: KA*NPTS   Yp: KA*NPTS   Rpart: NTILES*NPTS   Cpart: NTILES*NPTS
    //   total = (2*18 + 2*128)*16384*4 B ~= 18.3 MB
    float* Xp    = (float*)d_ws;
    float* Yp    = Xp + (size_t)KA * NPTS;
    float* Rpart = Yp + (size_t)KA * NPTS;
    float* Cpart = Rpart + (size_t)NTILES * NPTS;

    prep_kernel<<<NPTS / 256, 256, 0, stream>>>(set1, Xp, 1);
    prep_kernel<<<NPTS / 256, 256, 0, stream>>>(set2, Yp, 0);
    pairs_kernel<<<dim3(NTILES, NTILES), 256, 0, stream>>>(Xp, Yp, Rpart, Cpart);
    hipMemsetAsync(d_out, 0, sizeof(float), stream);
    finalize_kernel<<<2 * NPTS / 256, 256, 0, stream>>>(Rpart, Cpart, out);
}

// Round 2
// 174.128 us; speedup vs baseline: 1.1341x; 1.1341x over previous
//
#include <hip/hip_runtime.h>
#include <math.h>

#define NPTS 16384
#define DIM  16
#define TILE 128
#define NTILES (NPTS / TILE)   // 128
#define KH 64                  // padded split-K (halfs): [hi18, lo18, hi18, 0*10] / [hi18, hi18, lo18, 0*10]

typedef _Float16 f16x8 __attribute__((ext_vector_type(8)));
typedef float    f32x4 __attribute__((ext_vector_type(4)));

// ---------------------------------------------------------------------------
// prep: augmented fp32 vector a[18] with  <x',y'> = -0.5*rx*ry*||x-y||^2.
//   x' = rx*[x, -||x||^2/2, 1]   y' = ry*[y, 1, -||y||^2/2]
// fp16 hi/lo split; X rows = [ah, al, ah, pad], Y rows = [bh, bh, bl, pad] so
// a single K=64 f16 GEMM gives ah*bh + al*bh + ah*bl  (fp32-accurate dot).
// Storage is FRAGMENT-PACKED: group g=p/16, c=p%15? (p%16):
//   half-offset = g*1024 + seg*512 + quad*128 + c*8  holds k = seg*32+quad*8+j
// so the pairs kernel stages with a pure linear copy and every MFMA fragment
// read is ds_read_b128 at (base + lane*16B): zero bank conflicts.
// ---------------------------------------------------------------------------
__global__ __launch_bounds__(256) void prep_kernel(const float* __restrict__ src,
                                                   _Float16* __restrict__ dst,
                                                   int isX) {
    int p = blockIdx.x * 256 + threadIdx.x;
    if (p >= NPTS) return;
    const float4* s4 = (const float4*)(src + (size_t)p * DIM);
    float4 A = s4[0], B = s4[1], C = s4[2], D = s4[3];
    float v[DIM] = {A.x,A.y,A.z,A.w, B.x,B.y,B.z,B.w,
                    C.x,C.y,C.z,C.w, D.x,D.y,D.z,D.w};
    float n2 = 0.f;
#pragma unroll
    for (int k = 0; k < DIM; ++k) n2 = fmaf(v[k], v[k], n2);
    float r = 1.0f / (1.0f - n2);          // norms < 0.7 -> safe
    float a[18];
#pragma unroll
    for (int k = 0; k < DIM; ++k) a[k] = r * v[k];
    if (isX) { a[16] = -0.5f * r * n2; a[17] = r; }
    else     { a[16] = r;              a[17] = -0.5f * r * n2; }

    __attribute__((aligned(16))) _Float16 buf[KH];
#pragma unroll
    for (int k = 0; k < 18; ++k) {
        _Float16 hi = (_Float16)a[k];
        _Float16 lo = (_Float16)(a[k] - (float)hi);
        if (isX) { buf[k] = hi; buf[18 + k] = lo; buf[36 + k] = hi; }
        else     { buf[k] = hi; buf[18 + k] = hi; buf[36 + k] = lo; }
    }
#pragma unroll
    for (int k = 54; k < KH; ++k) buf[k] = (_Float16)0.f;

    int g = p >> 4, c = p & 15;
    const uint4* b4 = (const uint4*)buf;
#pragma unroll
    for (int sq = 0; sq < 8; ++sq) {
        size_t off = (size_t)g * 1024 + (size_t)(sq >> 2) * 512 + (size_t)(sq & 3) * 128 + (size_t)c * 8;
        *(uint4*)(dst + off) = b4[sq];
    }
}

// ---------------------------------------------------------------------------
// pairs: block = 128x128 tile, 256 threads = 4 waves in 2x2 (wr,wc), each wave
// a 64x64 region = 4x4 MFMA tiles of 16x16, K=64 => 32 MFMAs/wave.
// acc = <x',y'> (<= 0); nearest pair = max acc (arcosh monotone => no sqrt/log
// per pair). Row/col maxes via quad shuffles + LDS, partials to global.
// ---------------------------------------------------------------------------
__global__ __launch_bounds__(256, 3) void pairs_kernel(const _Float16* __restrict__ Xp,
                                                       const _Float16* __restrict__ Yp,
                                                       float* __restrict__ Rpart,
                                                       float* __restrict__ Cpart) {
    __shared__ _Float16 As[TILE * KH];   // 16 KB, fragment-packed
    __shared__ _Float16 Bs[TILE * KH];   // 16 KB
    __shared__ float rowred[TILE][2];
    __shared__ float colred[TILE][2];

    const int bi = blockIdx.x, bj = blockIdx.y;
    const int tid = threadIdx.x;
    const int lane = tid & 63, w = tid >> 6;
    const int wr = w >> 1, wc = w & 1;
    const int c = lane & 15, quad = lane >> 4;

    // stage: pure linear copy (prep already fragment-packed the data)
    {
        const uint4* gA = (const uint4*)(Xp + (size_t)bi * (TILE * KH));
        const uint4* gB = (const uint4*)(Yp + (size_t)bj * (TILE * KH));
        uint4* lA = (uint4*)As;
        uint4* lB = (uint4*)Bs;
#pragma unroll
        for (int e = 0; e < 4; ++e) {
            lA[tid + e * 256] = gA[tid + e * 256];
            lB[tid + e * 256] = gB[tid + e * 256];
        }
    }
    __syncthreads();

    f32x4 acc[4][4];
#pragma unroll
    for (int ti = 0; ti < 4; ++ti)
#pragma unroll
        for (int tj = 0; tj < 4; ++tj) acc[ti][tj] = (f32x4){0.f, 0.f, 0.f, 0.f};

    f16x8 bf[4][2];
#pragma unroll
    for (int tj = 0; tj < 4; ++tj) {
        bf[tj][0] = *(const f16x8*)&Bs[(wc * 4 + tj) * 1024 + lane * 8];
        bf[tj][1] = *(const f16x8*)&Bs[(wc * 4 + tj) * 1024 + 512 + lane * 8];
    }
#pragma unroll
    for (int ti = 0; ti < 4; ++ti) {
        f16x8 af0 = *(const f16x8*)&As[(wr * 4 + ti) * 1024 + lane * 8];
        f16x8 af1 = *(const f16x8*)&As[(wr * 4 + ti) * 1024 + 512 + lane * 8];
#pragma unroll
        for (int tj = 0; tj < 4; ++tj) {
            acc[ti][tj] = __builtin_amdgcn_mfma_f32_16x16x32_f16(af0, bf[tj][0], acc[ti][tj], 0, 0, 0);
            acc[ti][tj] = __builtin_amdgcn_mfma_f32_16x16x32_f16(af1, bf[tj][1], acc[ti][tj], 0, 0, 0);
        }
    }

    // C/D layout (measured, dtype-independent): n(Y) = lane&15, m(X) = quad*4+reg.
    // ---- row maxes: per (ti,reg) max over tj, then shuffle over c (bits 0-3) ----
#pragma unroll
    for (int ti = 0; ti < 4; ++ti)
#pragma unroll
        for (int reg = 0; reg < 4; ++reg) {
            float m = fmaxf(fmaxf(acc[ti][0][reg], acc[ti][1][reg]),
                            fmaxf(acc[ti][2][reg], acc[ti][3][reg]));
            m = fmaxf(m, __shfl_xor(m, 1, 64));
            m = fmaxf(m, __shfl_xor(m, 2, 64));
            m = fmaxf(m, __shfl_xor(m, 4, 64));
            m = fmaxf(m, __shfl_xor(m, 8, 64));
            if (c == 0) rowred[wr * 64 + ti * 16 + quad * 4 + reg][wc] = m;
        }

    // ---- col maxes: per tj max over (ti,reg), then shuffle over quad (bits 4-5) ----
#pragma unroll
    for (int tj = 0; tj < 4; ++tj) {
        float m = acc[0][tj][0];
#pragma unroll
        for (int ti = 0; ti < 4; ++ti)
#pragma unroll
            for (int reg = 0; reg < 4; ++reg) m = fmaxf(m, acc[ti][tj][reg]);
        m = fmaxf(m, __shfl_xor(m, 16, 64));
        m = fmaxf(m, __shfl_xor(m, 32, 64));
        if (quad == 0) colred[wc * 64 + tj * 16 + c][wr] = m;
    }

    __syncthreads();
    if (tid < TILE) {
        float rm = fmaxf(rowred[tid][0], rowred[tid][1]);
        Rpart[(size_t)bj * NPTS + bi * TILE + tid] = rm;
        float cm = fmaxf(colred[tid][0], colred[tid][1]);
        Cpart[(size_t)bi * NPTS + bj * TILE + tid] = cm;
    }
}

// ---------------------------------------------------------------------------
// finalize: reduce 128 partials per point, arcosh, mean, atomic-add scalar.
// t = -4*maxacc = u-1 >= 0 ;  arcosh(1+t) = log1p(t + sqrt(t*(t+2)))
// ---------------------------------------------------------------------------
__global__ __launch_bounds__(256) void finalize_kernel(const float* __restrict__ Rpart,
                                                       const float* __restrict__ Cpart,
                                                       float* __restrict__ out) {
    int idx = blockIdx.x * 256 + threadIdx.x;
    const bool isRow = (idx < NPTS);                 // uniform per block (256 | 16384)
    const float* P = isRow ? Rpart : Cpart;
    int i = isRow ? idx : idx - NPTS;
    float m = P[i];
    for (int s = 1; s < NTILES; ++s) m = fmaxf(m, P[(size_t)s * NPTS + i]);
    float t = -4.0f * m;
    float d = log1pf(t + sqrtf(t * (t + 2.0f)));
    float val = d * (1.0f / NPTS);

    __shared__ float sred[256];
    sred[threadIdx.x] = val;
    __syncthreads();
    for (int s = 128; s > 0; s >>= 1) {
        if (threadIdx.x < s) sred[threadIdx.x] += sred[threadIdx.x + s];
        __syncthreads();
    }
    if (threadIdx.x == 0) atomicAdd(out, sred[0]);
}

// ---------------------------------------------------------------------------
extern "C" void kernel_launch(void* const* d_in, const int* in_sizes, int n_in,
                              void* d_out, int out_size, void* d_ws, size_t ws_size,
                              hipStream_t stream) {
    const float* set1 = (const float*)d_in[0];
    const float* set2 = (const float*)d_in[1];
    float* out = (float*)d_out;

    // workspace: Xp 2MB (halfs), Yp 2MB, Rpart 8MB, Cpart 8MB  => 20MB
    _Float16* Xp = (_Float16*)d_ws;
    _Float16* Yp = Xp + (size_t)NPTS * KH;
    float* Rpart = (float*)(Yp + (size_t)NPTS * KH);
    float* Cpart = Rpart + (size_t)NTILES * NPTS;

    prep_kernel<<<NPTS / 256, 256, 0, stream>>>(set1, Xp, 1);
    prep_kernel<<<NPTS / 256, 256, 0, stream>>>(set2, Yp, 0);
    pairs_kernel<<<dim3(NTILES, NTILES), 256, 0, stream>>>(Xp, Yp, Rpart, Cpart);
    hipMemsetAsync(d_out, 0, sizeof(float), stream);
    finalize_kernel<<<2 * NPTS / 256, 256, 0, stream>>>(Rpart, Cpart, out);
}

// Round 3
// 115.535 us; speedup vs baseline: 1.7093x; 1.5071x over previous
//
#include <hip/hip_runtime.h>
#include <math.h>

#define NPTS 16384
#define DIM  16
#define KH   64                 // padded split-K halfs: X=[hi18,lo18,hi18,0*10], Y=[hi18,hi18,lo18,0*10]
#define CSPLIT 8
#define COLS_PER_BLOCK (NPTS / CSPLIT)        // 2048
#define CHUNK_COLS 256
#define NCHUNK (COLS_PER_BLOCK / CHUNK_COLS)  // 8
#define JT_PER_CHUNK (CHUNK_COLS / 16)        // 16
#define ROWS_PER_BLOCK 512
#define RBLK (NPTS / ROWS_PER_BLOCK)          // 32
#define MT 8                                   // 16-row M-tiles per wave (128 rows/wave)

typedef _Float16 f16x8 __attribute__((ext_vector_type(8)));
typedef float    f32x4 __attribute__((ext_vector_type(4)));

// ---------------------------------------------------------------------------
// prep: augmented vectors with <x',y'> = -0.5*rx*ry*||x-y||^2 (fp16 hi/lo
// split, fp32-accurate). FRAGMENT-PACKED layout: group g=p/16, c=p%16,
// half-offset = g*1024 + seg*512 + quad*128 + c*8 (= g*1024 + seg*512 + lane*8)
// so pairs reads fragments with linear ds_read_b128 / global b128, 0 conflicts.
// Also: init the atomicMin array to +inf-pattern and zero the output scalar
// (harness poisons d_out/d_ws to 0xAA before every launch).
// ---------------------------------------------------------------------------
__global__ __launch_bounds__(256) void prep_kernel(const float* __restrict__ s1,
                                                   const float* __restrict__ s2,
                                                   _Float16* __restrict__ Xp,
                                                   _Float16* __restrict__ Yp,
                                                   unsigned int* __restrict__ rowfinal,
                                                   float* __restrict__ out) {
    int b = blockIdx.x, tid = threadIdx.x;
    int idx = b * 256 + tid;                // 0..32767
    rowfinal[idx] = 0xFFFFFFFFu;            // uint-min identity (all real bits < this)
    if (idx == 0) out[0] = 0.f;

    int isX = (b < 64);
    const float* src = isX ? s1 : s2;
    _Float16* dst = isX ? Xp : Yp;
    int p = (isX ? b : b - 64) * 256 + tid;

    const float4* s4 = (const float4*)(src + (size_t)p * DIM);
    float4 A = s4[0], B = s4[1], C = s4[2], D = s4[3];
    float v[DIM] = {A.x,A.y,A.z,A.w, B.x,B.y,B.z,B.w,
                    C.x,C.y,C.z,C.w, D.x,D.y,D.z,D.w};
    float n2 = 0.f;
#pragma unroll
    for (int k = 0; k < DIM; ++k) n2 = fmaf(v[k], v[k], n2);
    float r = 1.0f / (1.0f - n2);           // norms < 0.7 -> safe
    float a[18];
#pragma unroll
    for (int k = 0; k < DIM; ++k) a[k] = r * v[k];
    if (isX) { a[16] = -0.5f * r * n2; a[17] = r; }
    else     { a[16] = r;              a[17] = -0.5f * r * n2; }

    __attribute__((aligned(16))) _Float16 buf[KH];
#pragma unroll
    for (int k = 0; k < 18; ++k) {
        _Float16 hi = (_Float16)a[k];
        _Float16 lo = (_Float16)(a[k] - (float)hi);
        if (isX) { buf[k] = hi; buf[18 + k] = lo; buf[36 + k] = hi; }
        else     { buf[k] = hi; buf[18 + k] = hi; buf[36 + k] = lo; }
    }
#pragma unroll
    for (int k = 54; k < KH; ++k) buf[k] = (_Float16)0.f;

    int g = p >> 4, c = p & 15;
    const uint4* b4 = (const uint4*)buf;
#pragma unroll
    for (int sq = 0; sq < 8; ++sq) {
        size_t off = (size_t)g * 1024 + (size_t)(sq >> 2) * 512 + (size_t)(sq & 3) * 128 + (size_t)c * 8;
        *(uint4*)(dst + off) = b4[sq];
    }
}

// ---------------------------------------------------------------------------
// pairs: 512 blocks (2 passes x 32 row-blocks x 8 col-splits), 256 thr = 4
// waves. Wave holds 128 rows of A in REGISTERS (16 b128 global loads, no LDS),
// sweeps 2048 cols in 256-col LDS chunks staged via global_load_lds width=16.
// Per 16-col tile: 2 ds_read_b128 + 16 MFMA + 32 fmax (running per-lane row
// max; arcosh monotone => compare raw accumulators). Cross-lane c-reduction
// once at the end, then atomicMin (uint) into rowfinal (acc<=0: more-negative
// float = larger uint, so float-max == uint-min).
// Pass 0: rows=set1 (term1); pass 1: rows=set2 (term2).
// ---------------------------------------------------------------------------
__global__ __launch_bounds__(256, 2) void pairs_kernel(const _Float16* __restrict__ Xp,
                                                       const _Float16* __restrict__ Yp,
                                                       unsigned int* __restrict__ rowfinal) {
    __shared__ __align__(16) _Float16 Bs[CHUNK_COLS * KH];   // 32 KB

    const int b = blockIdx.x;
    const int pass = b >> 8;                 // 256 blocks per pass
    const int within = b & 255;
    const int r  = within >> 3;              // row-block 0..31
    const int cs = within & 7;               // col-split 0..7

    const _Float16* Aset = pass ? Yp : Xp;
    const _Float16* Bset = pass ? Xp : Yp;
    unsigned int* outMin = rowfinal + pass * NPTS;

    const int tid = threadIdx.x;
    const int lane = tid & 63, w = tid >> 6;
    const int c = lane & 15, quad = lane >> 4;

    // ---- A fragments: 128 rows/wave, resident in registers for the whole sweep
    f16x8 af[MT][2];
#pragma unroll
    for (int t = 0; t < MT; ++t) {
        int g = r * 32 + w * 8 + t;
        af[t][0] = *(const f16x8*)&Aset[(size_t)g * 1024 + (size_t)lane * 8];
        af[t][1] = *(const f16x8*)&Aset[(size_t)g * 1024 + 512 + (size_t)lane * 8];
    }

    f32x4 rowmax[MT];
#pragma unroll
    for (int t = 0; t < MT; ++t)
        rowmax[t] = (f32x4){-INFINITY, -INFINITY, -INFINITY, -INFINITY};

    const char* Bbase = (const char*)Bset + (size_t)cs * ((size_t)COLS_PER_BLOCK * KH * 2);

    for (int ch = 0; ch < NCHUNK; ++ch) {
        // stage 32 KB chunk: linear copy, direct-to-LDS DMA (width 16)
        const char* gsrc = Bbase + (size_t)ch * (CHUNK_COLS * KH * 2) + (size_t)tid * 16;
        char* lb = (char*)Bs + (size_t)tid * 16;
#pragma unroll
        for (int e = 0; e < 8; ++e) {
            __builtin_amdgcn_global_load_lds(
                (const __attribute__((address_space(1))) unsigned int*)(gsrc + e * 4096),
                (__attribute__((address_space(3))) unsigned int*)(lb + e * 4096),
                16, 0, 0);
        }
        __syncthreads();   // drains vmcnt before barrier

#pragma unroll 4
        for (int jt = 0; jt < JT_PER_CHUNK; ++jt) {
            f16x8 bf0 = *(const f16x8*)&Bs[jt * 1024 + lane * 8];
            f16x8 bf1 = *(const f16x8*)&Bs[jt * 1024 + 512 + lane * 8];
#pragma unroll
            for (int t = 0; t < MT; ++t) {
                f32x4 acc = (f32x4){0.f, 0.f, 0.f, 0.f};
                acc = __builtin_amdgcn_mfma_f32_16x16x32_f16(af[t][0], bf0, acc, 0, 0, 0);
                acc = __builtin_amdgcn_mfma_f32_16x16x32_f16(af[t][1], bf1, acc, 0, 0, 0);
                rowmax[t][0] = fmaxf(rowmax[t][0], acc[0]);
                rowmax[t][1] = fmaxf(rowmax[t][1], acc[1]);
                rowmax[t][2] = fmaxf(rowmax[t][2], acc[2]);
                rowmax[t][3] = fmaxf(rowmax[t][3], acc[3]);
            }
        }
        __syncthreads();   // protect Bs before next chunk's DMA
    }

    // ---- once-per-block epilogue: reduce over the 16 c-lanes, then atomicMin
#pragma unroll
    for (int t = 0; t < MT; ++t) {
#pragma unroll
        for (int e = 0; e < 4; ++e) {
            float m = rowmax[t][e];
            m = fmaxf(m, __shfl_xor(m, 1, 64));
            m = fmaxf(m, __shfl_xor(m, 2, 64));
            m = fmaxf(m, __shfl_xor(m, 4, 64));
            m = fmaxf(m, __shfl_xor(m, 8, 64));
            if (c == 0) {
                int row = r * 512 + w * 128 + t * 16 + quad * 4 + e;
                atomicMin(&outMin[row], __float_as_uint(m));
            }
        }
    }
}

// ---------------------------------------------------------------------------
// finalize: 32768 winners -> arcosh -> mean -> atomicAdd scalar.
// t = -4*maxacc = u-1 >= 0 ;  arcosh(1+t) = log1p(t + sqrt(t*(t+2)))
// ---------------------------------------------------------------------------
__global__ __launch_bounds__(256) void finalize_kernel(const unsigned int* __restrict__ rowfinal,
                                                       float* __restrict__ out) {
    int idx = blockIdx.x * 256 + threadIdx.x;
    float f = __uint_as_float(rowfinal[idx]);     // max accumulator (<= 0)
    float t = -4.0f * f;
    float d = log1pf(t + sqrtf(t * (t + 2.0f)));
    float val = d * (1.0f / NPTS);

    __shared__ float sred[256];
    sred[threadIdx.x] = val;
    __syncthreads();
    for (int s = 128; s > 0; s >>= 1) {
        if (threadIdx.x < s) sred[threadIdx.x] += sred[threadIdx.x + s];
        __syncthreads();
    }
    if (threadIdx.x == 0) atomicAdd(out, sred[0]);
}

// ---------------------------------------------------------------------------
extern "C" void kernel_launch(void* const* d_in, const int* in_sizes, int n_in,
                              void* d_out, int out_size, void* d_ws, size_t ws_size,
                              hipStream_t stream) {
    const float* set1 = (const float*)d_in[0];
    const float* set2 = (const float*)d_in[1];
    float* out = (float*)d_out;

    // ws: Xp 2MB + Yp 2MB (halfs, fragment-packed) + rowfinal 128KB
    _Float16* Xp = (_Float16*)d_ws;
    _Float16* Yp = Xp + (size_t)NPTS * KH;
    unsigned int* rowfinal = (unsigned int*)(Yp + (size_t)NPTS * KH);

    prep_kernel<<<128, 256, 0, stream>>>(set1, set2, Xp, Yp, rowfinal, out);
    pairs_kernel<<<2 * RBLK * CSPLIT, 256, 0, stream>>>(Xp, Yp, rowfinal);
    finalize_kernel<<<2 * NPTS / 256, 256, 0, stream>>>(rowfinal, out);
}